// Round 1
// baseline (482.925 us; speedup 1.0000x reference)
//
#include <hip/hip_runtime.h>
#include <cmath>

// Fixed problem shape (from setup_inputs)
#define L_    8
#define B_    4
#define T_    2048
#define D_    1024
#define TTL_  1024
#define KSLOT 512          // max events per batch (k=410 total, so safe)
#define TC    512          // t-chunk for main kernel
#define NCH   (T_/TC)      // 4
#define DCH   4            // D_/256
#define ES    8            // event-split for excess kernel
#define SCH   8            // s-split for score kernel

__device__ __forceinline__ int waveRed(int v){
  for(int o=32;o>0;o>>=1) v += __shfl_xor(v,o,64);
  return v;
}

// ---------------------------------------------------------------------------
// Kernel A: top-k event selection (exact jax.lax.top_k tie-breaking),
// per-batch sorted event lists, and global weight w[s].
// One block, 1024 threads.
// ---------------------------------------------------------------------------
__global__ __launch_bounds__(1024) void kA(
    const float* __restrict__ pressure, const int* __restrict__ hptr,
    int k, int* __restrict__ evT, int* __restrict__ meta, float* __restrict__ w)
{
  __shared__ unsigned ku[B_*T_];
  __shared__ short ef[B_*T_];
  __shared__ int csum[1024];
  __shared__ int scnt;
  __shared__ int s_n[B_];
  const int tid = threadIdx.x;
  const int total = B_*T_;

  for(int i=tid;i<total;i+=1024){
    union{float f;unsigned u;} v; v.f = pressure[i];
    unsigned u = v.u;
    ku[i] = (u & 0x80000000u) ? ~u : (u | 0x80000000u);  // monotonic key
  }
  if(tid < B_) s_n[tid] = 0;
  __syncthreads();

  // bitwise k-th largest: largest p with count(key >= p) >= k
  unsigned p = 0;
  for(int bit=31;bit>=0;--bit){
    unsigned test = p | (1u<<bit);
    if(tid==0) scnt = 0;
    __syncthreads();
    int c=0;
    for(int i=tid;i<total;i+=1024) c += (ku[i] >= test) ? 1 : 0;
    c = waveRed(c);
    if((tid&63)==0) atomicAdd(&scnt, c);
    __syncthreads();
    if(scnt >= k) p = test;
    __syncthreads();
  }
  if(tid==0) scnt=0;
  __syncthreads();
  {
    int c=0;
    for(int i=tid;i<total;i+=1024) c += (ku[i] > p) ? 1 : 0;
    c = waveRed(c);
    if((tid&63)==0) atomicAdd(&scnt, c);
  }
  __syncthreads();
  const int needed = k - scnt;   // equals to select, lowest flat index first

  // event flags; each thread owns 8 contiguous elements
  int local = 0;
  for(int j=0;j<8;++j){
    int i = tid*8+j;
    unsigned u = ku[i];
    int f = 0;
    if(u > p) f = 1;
    else if(u == p){
      int r = 0;
      for(int q=0;q<i;++q) r += (ku[q]==p) ? 1 : 0;  // ties are rare
      f = (r < needed) ? 1 : 0;
    }
    ef[i] = (short)f;
    local += f;
  }
  csum[tid] = local;
  __syncthreads();

  // build per-batch sorted event lists (skip te == T-1: fe there is 0)
  for(int j=0;j<8;++j){
    int i = tid*8+j;
    if(ef[i]){
      int b = i / T_, t = i % T_;
      if(t != T_-1){
        int m = 0;
        int ch = i>>3;
        for(int q=(b*T_)>>3; q<ch; ++q) m += csum[q];
        for(int q=ch<<3; q<i; ++q) m += ef[q];
        evT[b*KSLOT + m] = t;
        atomicAdd(&s_n[b], 1);
      }
    }
  }
  __syncthreads();
  if(tid==0){
    int off=0;
    for(int b=0;b<B_;++b){ meta[b]=s_n[b]; meta[4+b]=off; off += s_n[b]; }
    meta[8] = off;  // total listed events (c>0)
  }

  // w[s] = sum_{t'=max(0,s-H)}^{s-1} 1/min(H, T-1-t')
  const int H = hptr[0];
  for(int s=tid;s<T_;s+=1024){
    float acc = 0.f;
    int lo = s - H; if(lo < 0) lo = 0;
    for(int t2=lo; t2<s; ++t2){
      int c2 = T_-1-t2; if(c2 > H) c2 = H;
      acc += 1.0f / (float)c2;
    }
    w[s] = acc;
  }
}

// ---------------------------------------------------------------------------
// Kernel B: main streaming pass over states.
// Computes S_all (weighted), S_ev (sum of fe at events), and stores event fe
// values into ckpt. Grid: L*B*NCH*DCH blocks of 256 threads.
// ---------------------------------------------------------------------------
__global__ __launch_bounds__(256) void kB(
    const float* __restrict__ states, const float* __restrict__ w,
    const int* __restrict__ evT, const int* __restrict__ meta,
    const int* __restrict__ hptr,
    float* __restrict__ S_all, float* __restrict__ S_ev, float* __restrict__ ckpt)
{
  int bx = blockIdx.x;
  const int dch = bx % DCH; bx /= DCH;
  const int tch = bx % NCH; bx /= NCH;
  const int b = bx % B_;  const int l = bx / B_;
  const int tid = threadIdx.x;
  const int d = dch*256 + tid;
  const int H = hptr[0];
  const int t0 = tch*TC, t1 = t0+TC;

  __shared__ float wloc[TC];
  __shared__ int sTe[KSLOT];
  __shared__ int sEn[KSLOT];
  __shared__ int sSl[KSLOT];
  __shared__ int sm0, sm1;

  const int n = meta[b], off = meta[4+b];
  for(int i=tid;i<TC;i+=256) wloc[i] = w[t0+i];
  for(int i=tid;i<n;i+=256) sTe[i] = evT[b*KSLOT+i];
  __syncthreads();
  if(tid==0){
    int m0=0; while(m0<n && sTe[m0] < t0) ++m0;
    int m1=m0; while(m1<n && sTe[m1] < t1) ++m1;
    sm0=m0; sm1=m1;
  }
  __syncthreads();
  const int m0=sm0, nev=sm1-sm0;
  for(int j=tid;j<nev;j+=256){
    int te = sTe[m0+j];
    int c = T_-1-te; if(c>H) c=H;   // c >= 1 here (te != T-1)
    sEn[j] = te + c;
    sSl[j] = off + m0 + j;
  }
  __syncthreads();

  int tmax = t1-1+H; if(tmax > T_-1) tmax = T_-1;
  const float* sp = states + (((size_t)(l*B_+b))*T_)*D_ + d;
  float aAll = 0.f, aEv = 0.f, R = 0.f;   // R is chunk-local prefix sum
  int ps = 0, pe = 0;
  for(int t=t0; t<=tmax; ++t){
    float x = sp[(size_t)t*D_];
    float sq = x*x;
    R += sq;
    if(t < t1) aAll = fmaf(wloc[t-t0], sq, aAll);
    if(ps < nev && sTe[m0+ps] == t){            // start mark: record prefix
      ckpt[((size_t)l*KSLOT + sSl[ps])*D_ + d] = R;
      ++ps;
    }
    while(pe < nev && sEn[pe] == t){            // end mark: finish fe
      size_t ci = ((size_t)l*KSLOT + sSl[pe])*D_ + d;
      float st = ckpt[ci];
      float fe = (R - st) / (float)(sEn[pe] - sTe[m0+pe]);
      ckpt[ci] = fe;
      aEv += fe;
      ++pe;
    }
  }
  atomicAdd(&S_all[l*D_+d], aAll);
  atomicAdd(&S_ev[l*D_+d], aEv);
}

// ---------------------------------------------------------------------------
// Kernel C: new_baseline -> out[1]
// ---------------------------------------------------------------------------
__global__ void kC(const float* __restrict__ S_all, const float* __restrict__ S_ev,
                   const float* __restrict__ baseline, float* __restrict__ out, int nonk)
{
  int i = blockIdx.x*256 + threadIdx.x;
  if(i < L_*D_){
    float obs = (S_all[i] - S_ev[i]) / (float)nonk;
    out[L_*D_ + i] = 0.99f*baseline[i] + 0.01f*obs;
  }
}

// ---------------------------------------------------------------------------
// Kernel D: excess sum over events (needs new_baseline)
// ---------------------------------------------------------------------------
__global__ __launch_bounds__(256) void kD(
    const float* __restrict__ ckpt, const int* __restrict__ meta,
    const float* __restrict__ nb, float* __restrict__ S_ex)
{
  int bx = blockIdx.x;
  const int ech = bx % ES; bx /= ES;
  const int dch = bx % DCH; const int l = bx / DCH;
  const int tid = threadIdx.x;
  const int d = dch*256 + tid;
  const int nev = meta[8];
  const int chunk = (nev + ES - 1) / ES;
  const int e0 = ech*chunk;
  int e1 = e0 + chunk; if(e1 > nev) e1 = nev;
  if(e1 <= e0) return;
  const float base = nb[l*D_ + d];
  float acc = 0.f;
  for(int e=e0;e<e1;++e){
    float fe = ckpt[((size_t)l*KSLOT + e)*D_ + d];
    acc += fmaxf(fe - base, 0.f);
  }
  atomicAdd(&S_ex[l*D_+d], acc);
}

// ---------------------------------------------------------------------------
// Kernel S2: age-weighted bank sums (partial over s-chunks)
// ---------------------------------------------------------------------------
__global__ __launch_bounds__(256) void kS2(
    const float* __restrict__ bank_ev, const int* __restrict__ bank_step,
    const int* __restrict__ csptr, float* __restrict__ Sscore)
{
  int bx = blockIdx.x;
  const int sch = bx % SCH; bx /= SCH;
  const int dch = bx % DCH; const int l = bx / DCH;
  const int tid = threadIdx.x;
  const int d = dch*256 + tid;
  const int scount = TTL_/SCH;   // 128
  const int s0 = sch*scount;
  __shared__ float wl[256];
  const int cs = csptr[0];
  if(tid < scount){
    int bs = bank_step[l*TTL_ + s0 + tid];
    float wgt = 0.f;
    if(bs >= 0){
      int a = cs - bs; if(a < 0) a = 0;
      wgt = exp2f(-(float)a * (1.0f/256.0f));
    }
    wl[tid] = wgt;
  }
  __syncthreads();
  float acc = 0.f;
  const float* bp = bank_ev + ((size_t)l*TTL_ + s0)*D_ + d;
  for(int j=0;j<scount;++j) acc = fmaf(wl[j], bp[(size_t)j*D_], acc);
  atomicAdd(&Sscore[l*D_+d], acc);
}

// ---------------------------------------------------------------------------
// Kernel E: finalize evidence -> out[0] and score -> out[2]
// ---------------------------------------------------------------------------
__global__ __launch_bounds__(256) void kE(
    const float* __restrict__ S_ex, const float* __restrict__ Sscore,
    const int* __restrict__ bank_step, const int* __restrict__ csptr,
    float* __restrict__ out, float kf)
{
  int bx = blockIdx.x;
  const int dch = bx % DCH; const int l = bx / DCH;
  const int tid = threadIdx.x;
  __shared__ float red[256];
  const int cs = csptr[0];
  float wacc = 0.f;
  for(int s=tid; s<TTL_; s+=256){
    int bs = bank_step[l*TTL_+s];
    if(bs >= 0){
      int a = cs - bs; if(a<0) a=0;
      wacc += exp2f(-(float)a * (1.0f/256.0f));
    }
  }
  red[tid] = wacc;
  __syncthreads();
  for(int st=128; st>0; st>>=1){ if(tid<st) red[tid] += red[tid+st]; __syncthreads(); }
  const float wsum = red[0];
  const int d = dch*256 + tid;
  const int i = l*D_ + d;
  out[i] = S_ex[i] / kf;
  float sc = 0.f;
  if(wsum > 0.f) sc = Sscore[i] / fmaxf(wsum, 1e-12f);
  out[2*L_*D_ + i] = sc;
}

// ---------------------------------------------------------------------------
extern "C" void kernel_launch(void* const* d_in, const int* in_sizes, int n_in,
                              void* d_out, int out_size, void* d_ws, size_t ws_size,
                              hipStream_t stream)
{
  const float* pressure  = (const float*)d_in[0];
  const float* states    = (const float*)d_in[1];
  const float* bank_ev   = (const float*)d_in[2];
  const float* baseline  = (const float*)d_in[3];
  const int*   bank_step = (const int*)d_in[4];
  const int*   csptr     = (const int*)d_in[5];
  const int*   hptr      = (const int*)d_in[6];
  float* out = (float*)d_out;

  const int total = B_*T_;
  const int k = (int)llround(0.05 * (double)total);   // 410

  // workspace layout
  char* ws = (char*)d_ws;
  float* w      = (float*)(ws + 0);        // T_ floats (8KB)
  int*   evT    = (int*)(ws + 8192);       // B_*KSLOT ints (8KB)
  int*   meta   = (int*)(ws + 16384);      // 16 ints
  float* S_all  = (float*)(ws + 32768);    // L*D
  float* S_ev   = (float*)(ws + 65536);
  float* S_ex   = (float*)(ws + 98304);
  float* Sscore = (float*)(ws + 131072);
  float* ckpt   = (float*)(ws + 163840);   // L*KSLOT*D floats (16MB)

  const size_t need = 163840 + (size_t)L_*KSLOT*D_*sizeof(float);
  if(ws_size < need) return;  // fail validation loudly rather than corrupt

  // zero the accumulation region (ws is NOT re-poisoned between replays)
  hipMemsetAsync(S_all, 0, 4*(size_t)L_*D_*sizeof(float), stream);

  kA<<<1, 1024, 0, stream>>>(pressure, hptr, k, evT, meta, w);
  kB<<<L_*B_*NCH*DCH, 256, 0, stream>>>(states, w, evT, meta, hptr, S_all, S_ev, ckpt);
  kC<<<(L_*D_+255)/256, 256, 0, stream>>>(S_all, S_ev, baseline, out, total - k);
  kD<<<L_*DCH*ES, 256, 0, stream>>>(ckpt, meta, out + L_*D_, S_ex);
  kS2<<<L_*DCH*SCH, 256, 0, stream>>>(bank_ev, bank_step, csptr, Sscore);
  kE<<<L_*DCH, 256, 0, stream>>>(S_ex, Sscore, bank_step, csptr, out, (float)k);
}

// Round 2
// 255.192 us; speedup vs baseline: 1.8924x; 1.8924x over previous
//
#include <hip/hip_runtime.h>
#include <cmath>
#include <climits>

// Fixed problem shape (from setup_inputs)
#define L_    8
#define B_    4
#define T_    2048
#define D_    1024
#define TTL_  1024
#define KSLOT 512          // max events per batch (k=410 total, so safe)
#define TC2   128          // t-chunk for main kernel
#define NCH2  (T_/TC2)     // 16
#define DCH   4            // D_/256 (used by small kernels)
#define ES    8            // event-split for excess kernel
#define SCH   8            // s-split for score kernel

__device__ __forceinline__ int waveRed(int v){
  for(int o=32;o>0;o>>=1) v += __shfl_xor(v,o,64);
  return v;
}

// ---------------------------------------------------------------------------
// Kernel A: top-k event selection (exact jax.lax.top_k tie-breaking),
// per-batch sorted event lists, and global weight w[s].
// One block, 1024 threads.
// ---------------------------------------------------------------------------
__global__ __launch_bounds__(1024) void kA(
    const float* __restrict__ pressure, const int* __restrict__ hptr,
    int k, int* __restrict__ evT, int* __restrict__ meta, float* __restrict__ w)
{
  __shared__ unsigned ku[B_*T_];
  __shared__ short ef[B_*T_];
  __shared__ int csum[1024];
  __shared__ int scnt;
  __shared__ int s_n[B_];
  const int tid = threadIdx.x;
  const int total = B_*T_;

  for(int i=tid;i<total;i+=1024){
    union{float f;unsigned u;} v; v.f = pressure[i];
    unsigned u = v.u;
    ku[i] = (u & 0x80000000u) ? ~u : (u | 0x80000000u);  // monotonic key
  }
  if(tid < B_) s_n[tid] = 0;
  __syncthreads();

  // bitwise k-th largest: largest p with count(key >= p) >= k
  unsigned p = 0;
  for(int bit=31;bit>=0;--bit){
    unsigned test = p | (1u<<bit);
    if(tid==0) scnt = 0;
    __syncthreads();
    int c=0;
    for(int i=tid;i<total;i+=1024) c += (ku[i] >= test) ? 1 : 0;
    c = waveRed(c);
    if((tid&63)==0) atomicAdd(&scnt, c);
    __syncthreads();
    if(scnt >= k) p = test;
    __syncthreads();
  }
  if(tid==0) scnt=0;
  __syncthreads();
  {
    int c=0;
    for(int i=tid;i<total;i+=1024) c += (ku[i] > p) ? 1 : 0;
    c = waveRed(c);
    if((tid&63)==0) atomicAdd(&scnt, c);
  }
  __syncthreads();
  const int needed = k - scnt;   // ties to select, lowest flat index first

  // event flags; each thread owns 8 contiguous elements
  int local = 0;
  for(int j=0;j<8;++j){
    int i = tid*8+j;
    unsigned u = ku[i];
    int f = 0;
    if(u > p) f = 1;
    else if(u == p){
      int r = 0;
      for(int q=0;q<i;++q) r += (ku[q]==p) ? 1 : 0;  // ties are rare
      f = (r < needed) ? 1 : 0;
    }
    ef[i] = (short)f;
    local += f;
  }
  csum[tid] = local;
  __syncthreads();

  // build per-batch sorted event lists (skip te == T-1: fe there is 0)
  for(int j=0;j<8;++j){
    int i = tid*8+j;
    if(ef[i]){
      int b = i / T_, t = i % T_;
      if(t != T_-1){
        int m = 0;
        int ch = i>>3;
        for(int q=(b*T_)>>3; q<ch; ++q) m += csum[q];
        for(int q=ch<<3; q<i; ++q) m += ef[q];
        evT[b*KSLOT + m] = t;
        atomicAdd(&s_n[b], 1);
      }
    }
  }
  __syncthreads();
  if(tid==0){
    int off=0;
    for(int b=0;b<B_;++b){ meta[b]=s_n[b]; meta[4+b]=off; off += s_n[b]; }
    meta[8] = off;  // total listed events
  }

  // w[s] = sum_{t'=max(0,s-H)}^{s-1} 1/min(H, T-1-t')
  const int H = hptr[0];
  for(int s=tid;s<T_;s+=1024){
    float acc = 0.f;
    int lo = s - H; if(lo < 0) lo = 0;
    for(int t2=lo; t2<s; ++t2){
      int c2 = T_-1-t2; if(c2 > H) c2 = H;
      acc += 1.0f / (float)c2;
    }
    w[s] = acc;
  }
}

// ---------------------------------------------------------------------------
// Kernel B: main streaming pass over states (float4, depth-2 prefetch).
// One block per (l,b,tchunk); 256 threads x float4 = full 1024-d row per t.
// Computes S_all (weighted), S_ev (sum of fe at events), event fe -> ckpt.
// ---------------------------------------------------------------------------
__global__ __launch_bounds__(256) void kB(
    const float* __restrict__ states, const float* __restrict__ w,
    const int* __restrict__ evT, const int* __restrict__ meta,
    const int* __restrict__ hptr,
    float* __restrict__ S_all, float* __restrict__ S_ev, float* __restrict__ ckpt)
{
  int bx = blockIdx.x;
  const int tch = bx % NCH2; bx /= NCH2;
  const int b = bx % B_;  const int l = bx / B_;
  const int tid = threadIdx.x;
  const int H = hptr[0];
  const int t0 = tch*TC2, t1 = t0+TC2;

  __shared__ float wloc[TC2];
  __shared__ int   sTe[KSLOT];
  __shared__ int   sEn[TC2+2];
  __shared__ int   sSl[TC2+2];
  __shared__ float sInv[TC2+2];

  const int n = meta[b], off = meta[4+b];
  for(int i=tid;i<TC2;i+=256) wloc[i] = w[t0+i];
  for(int i=tid;i<n;i+=256)   sTe[i]  = evT[b*KSLOT+i];
  __syncthreads();
  // ranks via block-wide counts (list is sorted): m0 = #(te<t0), m1 = #(te<t1)
  int a0 = (tid      < n && sTe[tid]      < t0) ? 1 : 0;
  int a1 = (tid+256  < n && sTe[tid+256]  < t0) ? 1 : 0;
  int b0 = (tid      < n && sTe[tid]      < t1) ? 1 : 0;
  int b1 = (tid+256  < n && sTe[tid+256]  < t1) ? 1 : 0;
  const int m0 = __syncthreads_count(a0) + __syncthreads_count(a1);
  const int m1 = __syncthreads_count(b0) + __syncthreads_count(b1);
  const int nev = m1 - m0;
  for(int j=tid;j<nev;j+=256){
    int te = sTe[m0+j];
    int c = T_-1-te; if(c>H) c=H;     // c >= 1 (te != T-1 excluded)
    sEn[j]  = te + c;
    sSl[j]  = off + m0 + j;
    sInv[j] = 1.0f/(float)c;
  }
  __syncthreads();

  int tmax = t1-1+H; if(tmax > T_-1) tmax = T_-1;
  const float4* sp = (const float4*)(states + ((size_t)(l*B_+b)*T_)*D_) + tid;
  float4 R = {0,0,0,0}, A = {0,0,0,0}, E = {0,0,0,0};
  int i0 = 0, i1 = 0;
  int nextS = (i0 < nev) ? sTe[m0]   : INT_MAX;
  int nextE = (i1 < nev) ? sEn[0]    : INT_MAX;

  // depth-2 prefetch
  float4 x  = sp[(size_t)t0*256];
  float4 xa = sp[(size_t)(t0+1)*256];

  // phase 1: [t0, t1) — weighted accumulation + start marks + early end marks
  for(int t=t0; t<t1; ++t){
    float4 xb = xa;
    int tp = t+2;
    if(tp <= tmax) xb = sp[(size_t)tp*256];
    float4 sq;
    sq.x = x.x*x.x; sq.y = x.y*x.y; sq.z = x.z*x.z; sq.w = x.w*x.w;
    R.x += sq.x; R.y += sq.y; R.z += sq.z; R.w += sq.w;
    const float wv = wloc[t-t0];
    A.x = fmaf(wv, sq.x, A.x); A.y = fmaf(wv, sq.y, A.y);
    A.z = fmaf(wv, sq.z, A.z); A.w = fmaf(wv, sq.w, A.w);
    if(t == nextS){
      float4* cp = (float4*)(ckpt + ((size_t)l*KSLOT + sSl[i0])*D_) + tid;
      *cp = R;
      ++i0; nextS = (i0 < nev) ? sTe[m0+i0] : INT_MAX;
    }
    while(t == nextE){
      float4* cp = (float4*)(ckpt + ((size_t)l*KSLOT + sSl[i1])*D_) + tid;
      float4 st = *cp;
      const float inv = sInv[i1];
      float4 fe;
      fe.x = (R.x-st.x)*inv; fe.y = (R.y-st.y)*inv;
      fe.z = (R.z-st.z)*inv; fe.w = (R.w-st.w)*inv;
      *cp = fe;
      E.x += fe.x; E.y += fe.y; E.z += fe.z; E.w += fe.w;
      ++i1; nextE = (i1 < nev) ? sEn[i1] : INT_MAX;
    }
    x = xa; xa = xb;
  }
  // phase 2: [t1, tmax] — prefix + end marks only
  for(int t=t1; t<=tmax; ++t){
    float4 xb = xa;
    int tp = t+2;
    if(tp <= tmax) xb = sp[(size_t)tp*256];
    R.x += x.x*x.x; R.y += x.y*x.y; R.z += x.z*x.z; R.w += x.w*x.w;
    while(t == nextE){
      float4* cp = (float4*)(ckpt + ((size_t)l*KSLOT + sSl[i1])*D_) + tid;
      float4 st = *cp;
      const float inv = sInv[i1];
      float4 fe;
      fe.x = (R.x-st.x)*inv; fe.y = (R.y-st.y)*inv;
      fe.z = (R.z-st.z)*inv; fe.w = (R.w-st.w)*inv;
      *cp = fe;
      E.x += fe.x; E.y += fe.y; E.z += fe.z; E.w += fe.w;
      ++i1; nextE = (i1 < nev) ? sEn[i1] : INT_MAX;
    }
    x = xa; xa = xb;
  }

  float* sa = S_all + l*D_ + tid*4;
  float* se = S_ev  + l*D_ + tid*4;
  atomicAdd(sa+0, A.x); atomicAdd(sa+1, A.y); atomicAdd(sa+2, A.z); atomicAdd(sa+3, A.w);
  atomicAdd(se+0, E.x); atomicAdd(se+1, E.y); atomicAdd(se+2, E.z); atomicAdd(se+3, E.w);
}

// ---------------------------------------------------------------------------
// Kernel C: new_baseline -> out[1]
// ---------------------------------------------------------------------------
__global__ void kC(const float* __restrict__ S_all, const float* __restrict__ S_ev,
                   const float* __restrict__ baseline, float* __restrict__ out, int nonk)
{
  int i = blockIdx.x*256 + threadIdx.x;
  if(i < L_*D_){
    float obs = (S_all[i] - S_ev[i]) / (float)nonk;
    out[L_*D_ + i] = 0.99f*baseline[i] + 0.01f*obs;
  }
}

// ---------------------------------------------------------------------------
// Kernel D: excess sum over events (needs new_baseline)
// ---------------------------------------------------------------------------
__global__ __launch_bounds__(256) void kD(
    const float* __restrict__ ckpt, const int* __restrict__ meta,
    const float* __restrict__ nb, float* __restrict__ S_ex)
{
  int bx = blockIdx.x;
  const int ech = bx % ES; bx /= ES;
  const int dch = bx % DCH; const int l = bx / DCH;
  const int tid = threadIdx.x;
  const int d = dch*256 + tid;
  const int nev = meta[8];
  const int chunk = (nev + ES - 1) / ES;
  const int e0 = ech*chunk;
  int e1 = e0 + chunk; if(e1 > nev) e1 = nev;
  if(e1 <= e0) return;
  const float base = nb[l*D_ + d];
  float acc = 0.f;
  for(int e=e0;e<e1;++e){
    float fe = ckpt[((size_t)l*KSLOT + e)*D_ + d];
    acc += fmaxf(fe - base, 0.f);
  }
  atomicAdd(&S_ex[l*D_+d], acc);
}

// ---------------------------------------------------------------------------
// Kernel S2: age-weighted bank sums (partial over s-chunks)
// ---------------------------------------------------------------------------
__global__ __launch_bounds__(256) void kS2(
    const float* __restrict__ bank_ev, const int* __restrict__ bank_step,
    const int* __restrict__ csptr, float* __restrict__ Sscore)
{
  int bx = blockIdx.x;
  const int sch = bx % SCH; bx /= SCH;
  const int dch = bx % DCH; const int l = bx / DCH;
  const int tid = threadIdx.x;
  const int d = dch*256 + tid;
  const int scount = TTL_/SCH;   // 128
  const int s0 = sch*scount;
  __shared__ float wl[256];
  const int cs = csptr[0];
  if(tid < scount){
    int bs = bank_step[l*TTL_ + s0 + tid];
    float wgt = 0.f;
    if(bs >= 0){
      int a = cs - bs; if(a < 0) a = 0;
      wgt = exp2f(-(float)a * (1.0f/256.0f));
    }
    wl[tid] = wgt;
  }
  __syncthreads();
  float acc = 0.f;
  const float* bp = bank_ev + ((size_t)l*TTL_ + s0)*D_ + d;
  for(int j=0;j<scount;++j) acc = fmaf(wl[j], bp[(size_t)j*D_], acc);
  atomicAdd(&Sscore[l*D_+d], acc);
}

// ---------------------------------------------------------------------------
// Kernel E: finalize evidence -> out[0] and score -> out[2]
// ---------------------------------------------------------------------------
__global__ __launch_bounds__(256) void kE(
    const float* __restrict__ S_ex, const float* __restrict__ Sscore,
    const int* __restrict__ bank_step, const int* __restrict__ csptr,
    float* __restrict__ out, float kf)
{
  int bx = blockIdx.x;
  const int dch = bx % DCH; const int l = bx / DCH;
  const int tid = threadIdx.x;
  __shared__ float red[256];
  const int cs = csptr[0];
  float wacc = 0.f;
  for(int s=tid; s<TTL_; s+=256){
    int bs = bank_step[l*TTL_+s];
    if(bs >= 0){
      int a = cs - bs; if(a<0) a=0;
      wacc += exp2f(-(float)a * (1.0f/256.0f));
    }
  }
  red[tid] = wacc;
  __syncthreads();
  for(int st=128; st>0; st>>=1){ if(tid<st) red[tid] += red[tid+st]; __syncthreads(); }
  const float wsum = red[0];
  const int d = dch*256 + tid;
  const int i = l*D_ + d;
  out[i] = S_ex[i] / kf;
  float sc = 0.f;
  if(wsum > 0.f) sc = Sscore[i] / fmaxf(wsum, 1e-12f);
  out[2*L_*D_ + i] = sc;
}

// ---------------------------------------------------------------------------
extern "C" void kernel_launch(void* const* d_in, const int* in_sizes, int n_in,
                              void* d_out, int out_size, void* d_ws, size_t ws_size,
                              hipStream_t stream)
{
  const float* pressure  = (const float*)d_in[0];
  const float* states    = (const float*)d_in[1];
  const float* bank_ev   = (const float*)d_in[2];
  const float* baseline  = (const float*)d_in[3];
  const int*   bank_step = (const int*)d_in[4];
  const int*   csptr     = (const int*)d_in[5];
  const int*   hptr      = (const int*)d_in[6];
  float* out = (float*)d_out;

  const int total = B_*T_;
  const int k = (int)llround(0.05 * (double)total);   // 410

  // workspace layout
  char* ws = (char*)d_ws;
  float* w      = (float*)(ws + 0);        // T_ floats (8KB)
  int*   evT    = (int*)(ws + 8192);       // B_*KSLOT ints (8KB)
  int*   meta   = (int*)(ws + 16384);      // 16 ints
  float* S_all  = (float*)(ws + 32768);    // L*D
  float* S_ev   = (float*)(ws + 65536);
  float* S_ex   = (float*)(ws + 98304);
  float* Sscore = (float*)(ws + 131072);
  float* ckpt   = (float*)(ws + 163840);   // L*KSLOT*D floats (16MB)

  const size_t need = 163840 + (size_t)L_*KSLOT*D_*sizeof(float);
  if(ws_size < need) return;

  // zero the accumulation regions (ws is NOT re-poisoned between replays)
  hipMemsetAsync(S_all, 0, 4*(size_t)L_*D_*sizeof(float), stream);

  kA<<<1, 1024, 0, stream>>>(pressure, hptr, k, evT, meta, w);
  kB<<<L_*B_*NCH2, 256, 0, stream>>>(states, w, evT, meta, hptr, S_all, S_ev, ckpt);
  kC<<<(L_*D_+255)/256, 256, 0, stream>>>(S_all, S_ev, baseline, out, total - k);
  kD<<<L_*DCH*ES, 256, 0, stream>>>(ckpt, meta, out + L_*D_, S_ex);
  kS2<<<L_*DCH*SCH, 256, 0, stream>>>(bank_ev, bank_step, csptr, Sscore);
  kE<<<L_*DCH, 256, 0, stream>>>(S_ex, Sscore, bank_step, csptr, out, (float)k);
}

// Round 3
// 195.854 us; speedup vs baseline: 2.4657x; 1.3030x over previous
//
#include <hip/hip_runtime.h>
#include <cmath>
#include <climits>

// Fixed problem shape (from setup_inputs)
#define L_    8
#define B_    4
#define T_    2048
#define D_    1024
#define TTL_  1024
#define KSLOT 512          // max events per batch (k=410 total, so safe)
#define TC2   128          // t-chunk for main kernel
#define NCH2  (T_/TC2)     // 16
#define DCH   4            // D_/256 (used by small kernels)
#define ES    8            // event-split for excess kernel
#define SCH   8            // s-split for score kernel
#define TIEMAX 256

__device__ __forceinline__ int waveRed(int v){
  for(int o=32;o>0;o>>=1) v += __shfl_xor(v,o,64);
  return v;
}

// ---------------------------------------------------------------------------
// Kernel A: top-k event selection (exact jax.lax.top_k tie-breaking),
// per-batch sorted event lists, and global weight w[s].
// One block, 1024 threads.
// ---------------------------------------------------------------------------
__global__ __launch_bounds__(1024) void kA(
    const float* __restrict__ pressure, const int* __restrict__ hptr,
    int k, int* __restrict__ evT, int* __restrict__ meta, float* __restrict__ w)
{
  __shared__ unsigned ku[B_*T_];
  __shared__ short ef[B_*T_];
  __shared__ int csum[1024];
  __shared__ int scnt;
  __shared__ int s_n[B_];
  __shared__ int tieIdx[TIEMAX];
  __shared__ int tieCnt;
  const int tid = threadIdx.x;
  const int total = B_*T_;

  for(int i=tid;i<total;i+=1024){
    union{float f;unsigned u;} v; v.f = pressure[i];
    unsigned u = v.u;
    ku[i] = (u & 0x80000000u) ? ~u : (u | 0x80000000u);  // monotonic key
  }
  if(tid < B_) s_n[tid] = 0;
  if(tid == 0) tieCnt = 0;
  __syncthreads();

  // bitwise k-th largest: largest p with count(key >= p) >= k
  unsigned p = 0;
  for(int bit=31;bit>=0;--bit){
    unsigned test = p | (1u<<bit);
    if(tid==0) scnt = 0;
    __syncthreads();
    int c=0;
    for(int i=tid;i<total;i+=1024) c += (ku[i] >= test) ? 1 : 0;
    c = waveRed(c);
    if((tid&63)==0) atomicAdd(&scnt, c);
    __syncthreads();
    if(scnt >= k) p = test;
    __syncthreads();
  }
  if(tid==0) scnt=0;
  __syncthreads();
  {
    int c=0;
    for(int i=tid;i<total;i+=1024) c += (ku[i] > p) ? 1 : 0;
    c = waveRed(c);
    if((tid&63)==0) atomicAdd(&scnt, c);
  }
  // collect tie indices while counting strict-greater
  for(int i=tid;i<total;i+=1024){
    if(ku[i]==p){ int pos=atomicAdd(&tieCnt,1); if(pos<TIEMAX) tieIdx[pos]=i; }
  }
  __syncthreads();
  const int needed = k - scnt;   // ties to select, lowest flat index first

  // base event flags (strict greater)
  for(int j=0;j<8;++j){
    int i = tid*8+j;
    ef[i] = (ku[i] > p) ? (short)1 : (short)0;
  }
  __syncthreads();

  if(tieCnt <= TIEMAX){
    // serial selection of `needed` smallest tie indices (tieCnt tiny in practice)
    if(tid==0){
      int cnt = tieCnt;
      for(int sel=0; sel<needed; ++sel){
        int best=INT_MAX, bi=-1;
        for(int q=0;q<cnt;++q){ int vv=tieIdx[q]; if(vv>=0 && vv<best){best=vv;bi=q;} }
        if(bi>=0){ tieIdx[bi]=-1; ef[best]=1; }
      }
    }
  } else {
    // pathological fallback: per-element rank scan (correct, slow, never hit)
    for(int j=0;j<8;++j){
      int i = tid*8+j;
      if(ku[i]==p){
        int r=0;
        for(int q=0;q<i;++q) r += (ku[q]==p) ? 1 : 0;
        if(r < needed) ef[i]=1;
      }
    }
  }
  __syncthreads();

  // per-thread counts over final flags
  {
    int local=0;
    for(int j=0;j<8;++j) local += ef[tid*8+j];
    csum[tid]=local;
  }
  __syncthreads();

  // build per-batch sorted event lists (skip te == T-1: fe there is 0)
  for(int j=0;j<8;++j){
    int i = tid*8+j;
    if(ef[i]){
      int b = i / T_, t = i % T_;
      if(t != T_-1){
        int m = 0;
        int ch = i>>3;
        for(int q=(b*T_)>>3; q<ch; ++q) m += csum[q];
        for(int q=ch<<3; q<i; ++q) m += ef[q];
        evT[b*KSLOT + m] = t;
        atomicAdd(&s_n[b], 1);
      }
    }
  }
  __syncthreads();
  if(tid==0){
    int off=0;
    for(int b=0;b<B_;++b){ meta[b]=s_n[b]; meta[4+b]=off; off += s_n[b]; }
    meta[8] = off;  // total listed events
  }

  // w[s] = sum_{t'=max(0,s-H)}^{s-1} 1/min(H, T-1-t')
  const int H = hptr[0];
  for(int s=tid;s<T_;s+=1024){
    float acc = 0.f;
    int lo = s - H; if(lo < 0) lo = 0;
    for(int t2=lo; t2<s; ++t2){
      int c2 = T_-1-t2; if(c2 > H) c2 = H;
      acc += 1.0f / (float)c2;
    }
    w[s] = acc;
  }
}

// ---------------------------------------------------------------------------
// Kernel B: main streaming pass over states.
// Batch-8 register double-buffered loads; marks behind uniform batch guard
// so the steady-state loop has NO conditional memory ops (counted vmcnt).
// One block per (l,b,tchunk); 256 threads x float4 = full 1024-d row per t.
// ---------------------------------------------------------------------------
__global__ __launch_bounds__(256) void kB(
    const float* __restrict__ states, const float* __restrict__ w,
    const int* __restrict__ evT, const int* __restrict__ meta,
    const int* __restrict__ hptr,
    float* __restrict__ S_all, float* __restrict__ S_ev, float* __restrict__ ckpt)
{
  int bx = blockIdx.x;
  const int tch = bx % NCH2; bx /= NCH2;
  const int b = bx % B_;  const int l = bx / B_;
  const int tid = threadIdx.x;
  const int H = hptr[0];
  const int t0 = tch*TC2, t1 = t0+TC2;

  __shared__ float wloc[TC2];
  __shared__ int   sTe[KSLOT];
  __shared__ int   sEn[TC2+2];
  __shared__ int   sSl[TC2+2];
  __shared__ float sInv[TC2+2];

  const int n = meta[b], off = meta[4+b];
  for(int i=tid;i<TC2;i+=256) wloc[i] = w[t0+i];
  for(int i=tid;i<n;i+=256)   sTe[i]  = evT[b*KSLOT+i];
  __syncthreads();
  // ranks via block-wide counts (list is sorted): m0 = #(te<t0), m1 = #(te<t1)
  int a0 = (tid      < n && sTe[tid]      < t0) ? 1 : 0;
  int a1 = (tid+256  < n && sTe[tid+256]  < t0) ? 1 : 0;
  int b0 = (tid      < n && sTe[tid]      < t1) ? 1 : 0;
  int b1 = (tid+256  < n && sTe[tid+256]  < t1) ? 1 : 0;
  const int m0 = __syncthreads_count(a0) + __syncthreads_count(a1);
  const int m1 = __syncthreads_count(b0) + __syncthreads_count(b1);
  const int nev = m1 - m0;
  for(int j=tid;j<nev;j+=256){
    int te = sTe[m0+j];
    int c = T_-1-te; if(c>H) c=H;     // c >= 1 (te != T-1 excluded)
    sEn[j]  = te + c;
    sSl[j]  = off + m0 + j;
    sInv[j] = 1.0f/(float)c;
  }
  __syncthreads();

  int tmax = t1-1+H; if(tmax > T_-1) tmax = T_-1;
  const int len = tmax - t0 + 1;
  const int nfull = len >> 3;       // full batches of 8 (len%8==0 when H=64)
  const float4* sp = (const float4*)(states + ((size_t)(l*B_+b)*T_)*D_) + tid;

  float4 R = {0,0,0,0}, A = {0,0,0,0}, E = {0,0,0,0};
  int i0 = 0, i1 = 0;
  int nextS = (nev > 0) ? sTe[m0] : INT_MAX;
  int nextE = (nev > 0) ? sEn[0]  : INT_MAX;

  float4 v[8], u[8];
  if(nfull > 0){
    #pragma unroll
    for(int j=0;j<8;++j) v[j] = sp[(size_t)(t0+j)*256];
  }
  for(int nb=0; nb<nfull; ++nb){
    const int tb = t0 + nb*8;
    if(nb+1 < nfull){
      #pragma unroll
      for(int j=0;j<8;++j) u[j] = sp[(size_t)(tb+8+j)*256];
    }
    const bool hasMark = (nextS < tb+8) || (nextE < tb+8);
    if(!hasMark){
      // fast path: pure register math, no conditional memory ops
      #pragma unroll
      for(int j=0;j<8;++j){
        float4 x = v[j];
        float sx=x.x*x.x, sy=x.y*x.y, sz=x.z*x.z, sw=x.w*x.w;
        R.x+=sx; R.y+=sy; R.z+=sz; R.w+=sw;
        const int idx = tb + j - t0;
        const float wv = (idx < TC2) ? wloc[idx] : 0.0f;
        A.x=fmaf(wv,sx,A.x); A.y=fmaf(wv,sy,A.y);
        A.z=fmaf(wv,sz,A.z); A.w=fmaf(wv,sw,A.w);
      }
    } else {
      #pragma unroll
      for(int j=0;j<8;++j){
        float4 x = v[j];
        float sx=x.x*x.x, sy=x.y*x.y, sz=x.z*x.z, sw=x.w*x.w;
        R.x+=sx; R.y+=sy; R.z+=sz; R.w+=sw;
        const int idx = tb + j - t0;
        const float wv = (idx < TC2) ? wloc[idx] : 0.0f;
        A.x=fmaf(wv,sx,A.x); A.y=fmaf(wv,sy,A.y);
        A.z=fmaf(wv,sz,A.z); A.w=fmaf(wv,sw,A.w);
        const int t = tb + j;
        if(t == nextS){
          float4* cp = (float4*)(ckpt + ((size_t)l*KSLOT + sSl[i0])*D_) + tid;
          *cp = R;
          ++i0; nextS = (i0 < nev) ? sTe[m0+i0] : INT_MAX;
        }
        while(t == nextE){
          float4* cp = (float4*)(ckpt + ((size_t)l*KSLOT + sSl[i1])*D_) + tid;
          float4 st = *cp;
          const float inv = sInv[i1];
          float4 fe = {(R.x-st.x)*inv, (R.y-st.y)*inv, (R.z-st.z)*inv, (R.w-st.w)*inv};
          *cp = fe;
          E.x+=fe.x; E.y+=fe.y; E.z+=fe.z; E.w+=fe.w;
          ++i1; nextE = (i1 < nev) ? sEn[i1] : INT_MAX;
        }
      }
    }
    #pragma unroll
    for(int j=0;j<8;++j) v[j] = u[j];
  }
  // generic-H tail (not executed when H=64: len is a multiple of 8)
  for(int t=t0+nfull*8; t<=tmax; ++t){
    float4 x = sp[(size_t)t*256];
    float sx=x.x*x.x, sy=x.y*x.y, sz=x.z*x.z, sw=x.w*x.w;
    R.x+=sx; R.y+=sy; R.z+=sz; R.w+=sw;
    const int idx = t - t0;
    const float wv = (idx < TC2) ? wloc[idx] : 0.0f;
    A.x=fmaf(wv,sx,A.x); A.y=fmaf(wv,sy,A.y);
    A.z=fmaf(wv,sz,A.z); A.w=fmaf(wv,sw,A.w);
    if(t == nextS){
      float4* cp = (float4*)(ckpt + ((size_t)l*KSLOT + sSl[i0])*D_) + tid;
      *cp = R;
      ++i0; nextS = (i0 < nev) ? sTe[m0+i0] : INT_MAX;
    }
    while(t == nextE){
      float4* cp = (float4*)(ckpt + ((size_t)l*KSLOT + sSl[i1])*D_) + tid;
      float4 st = *cp;
      const float inv = sInv[i1];
      float4 fe = {(R.x-st.x)*inv, (R.y-st.y)*inv, (R.z-st.z)*inv, (R.w-st.w)*inv};
      *cp = fe;
      E.x+=fe.x; E.y+=fe.y; E.z+=fe.z; E.w+=fe.w;
      ++i1; nextE = (i1 < nev) ? sEn[i1] : INT_MAX;
    }
  }

  float* sa = S_all + l*D_ + tid*4;
  float* se = S_ev  + l*D_ + tid*4;
  atomicAdd(sa+0, A.x); atomicAdd(sa+1, A.y); atomicAdd(sa+2, A.z); atomicAdd(sa+3, A.w);
  atomicAdd(se+0, E.x); atomicAdd(se+1, E.y); atomicAdd(se+2, E.z); atomicAdd(se+3, E.w);
}

// ---------------------------------------------------------------------------
// Kernel D: baseline EMA (fused, was kC) + excess sum over events
// ---------------------------------------------------------------------------
__global__ __launch_bounds__(256) void kD(
    const float* __restrict__ ckpt, const int* __restrict__ meta,
    const float* __restrict__ S_all, const float* __restrict__ S_ev,
    const float* __restrict__ baseline, float* __restrict__ out,
    float* __restrict__ S_ex, int nonk)
{
  int bx = blockIdx.x;
  const int ech = bx % ES; bx /= ES;
  const int dch = bx % DCH; const int l = bx / DCH;
  const int tid = threadIdx.x;
  const int d = dch*256 + tid;
  const int i = l*D_ + d;
  const float obs = (S_all[i] - S_ev[i]) / (float)nonk;
  const float nb = 0.99f*baseline[i] + 0.01f*obs;
  if(ech == 0) out[L_*D_ + i] = nb;   // new_baseline output, written once
  const int nev = meta[8];
  const int chunk = (nev + ES - 1) / ES;
  const int e0 = ech*chunk;
  int e1 = e0 + chunk; if(e1 > nev) e1 = nev;
  if(e1 <= e0) return;
  float acc = 0.f;
  for(int e=e0;e<e1;++e){
    float fe = ckpt[((size_t)l*KSLOT + e)*D_ + d];
    acc += fmaxf(fe - nb, 0.f);
  }
  atomicAdd(&S_ex[l*D_+d], acc);
}

// ---------------------------------------------------------------------------
// Kernel S2: age-weighted bank sums (partial over s-chunks)
// ---------------------------------------------------------------------------
__global__ __launch_bounds__(256) void kS2(
    const float* __restrict__ bank_ev, const int* __restrict__ bank_step,
    const int* __restrict__ csptr, float* __restrict__ Sscore)
{
  int bx = blockIdx.x;
  const int sch = bx % SCH; bx /= SCH;
  const int dch = bx % DCH; const int l = bx / DCH;
  const int tid = threadIdx.x;
  const int d = dch*256 + tid;
  const int scount = TTL_/SCH;   // 128
  const int s0 = sch*scount;
  __shared__ float wl[256];
  const int cs = csptr[0];
  if(tid < scount){
    int bs = bank_step[l*TTL_ + s0 + tid];
    float wgt = 0.f;
    if(bs >= 0){
      int a = cs - bs; if(a < 0) a = 0;
      wgt = exp2f(-(float)a * (1.0f/256.0f));
    }
    wl[tid] = wgt;
  }
  __syncthreads();
  float acc0 = 0.f, acc1 = 0.f;
  const float* bp = bank_ev + ((size_t)l*TTL_ + s0)*D_ + d;
  for(int j=0;j<scount;j+=2){
    acc0 = fmaf(wl[j],   bp[(size_t)j*D_],     acc0);
    acc1 = fmaf(wl[j+1], bp[(size_t)(j+1)*D_], acc1);
  }
  atomicAdd(&Sscore[l*D_+d], acc0+acc1);
}

// ---------------------------------------------------------------------------
// Kernel E: finalize evidence -> out[0] and score -> out[2]
// ---------------------------------------------------------------------------
__global__ __launch_bounds__(256) void kE(
    const float* __restrict__ S_ex, const float* __restrict__ Sscore,
    const int* __restrict__ bank_step, const int* __restrict__ csptr,
    float* __restrict__ out, float kf)
{
  int bx = blockIdx.x;
  const int dch = bx % DCH; const int l = bx / DCH;
  const int tid = threadIdx.x;
  __shared__ float red[256];
  const int cs = csptr[0];
  float wacc = 0.f;
  for(int s=tid; s<TTL_; s+=256){
    int bs = bank_step[l*TTL_+s];
    if(bs >= 0){
      int a = cs - bs; if(a<0) a=0;
      wacc += exp2f(-(float)a * (1.0f/256.0f));
    }
  }
  red[tid] = wacc;
  __syncthreads();
  for(int st=128; st>0; st>>=1){ if(tid<st) red[tid] += red[tid+st]; __syncthreads(); }
  const float wsum = red[0];
  const int d = dch*256 + tid;
  const int i = l*D_ + d;
  out[i] = S_ex[i] / kf;
  float sc = 0.f;
  if(wsum > 0.f) sc = Sscore[i] / fmaxf(wsum, 1e-12f);
  out[2*L_*D_ + i] = sc;
}

// ---------------------------------------------------------------------------
extern "C" void kernel_launch(void* const* d_in, const int* in_sizes, int n_in,
                              void* d_out, int out_size, void* d_ws, size_t ws_size,
                              hipStream_t stream)
{
  const float* pressure  = (const float*)d_in[0];
  const float* states    = (const float*)d_in[1];
  const float* bank_ev   = (const float*)d_in[2];
  const float* baseline  = (const float*)d_in[3];
  const int*   bank_step = (const int*)d_in[4];
  const int*   csptr     = (const int*)d_in[5];
  const int*   hptr      = (const int*)d_in[6];
  float* out = (float*)d_out;

  const int total = B_*T_;
  const int k = (int)llround(0.05 * (double)total);   // 410

  // workspace layout
  char* ws = (char*)d_ws;
  float* w      = (float*)(ws + 0);        // T_ floats (8KB)
  int*   evT    = (int*)(ws + 8192);       // B_*KSLOT ints (8KB)
  int*   meta   = (int*)(ws + 16384);      // 16 ints
  float* S_all  = (float*)(ws + 32768);    // L*D (32KB)
  float* S_ev   = (float*)(ws + 65536);
  float* S_ex   = (float*)(ws + 98304);
  float* Sscore = (float*)(ws + 131072);
  float* ckpt   = (float*)(ws + 163840);   // L*KSLOT*D floats (16MB)

  const size_t need = 163840 + (size_t)L_*KSLOT*D_*sizeof(float);
  if(ws_size < need) return;

  // zero the four accumulation regions (contiguous 32KB-apart blocks)
  hipMemsetAsync(S_all, 0, 4*(size_t)L_*D_*sizeof(float), stream);

  kA<<<1, 1024, 0, stream>>>(pressure, hptr, k, evT, meta, w);
  kB<<<L_*B_*NCH2, 256, 0, stream>>>(states, w, evT, meta, hptr, S_all, S_ev, ckpt);
  kD<<<L_*DCH*ES, 256, 0, stream>>>(ckpt, meta, S_all, S_ev, baseline, out, S_ex, total - k);
  kS2<<<L_*DCH*SCH, 256, 0, stream>>>(bank_ev, bank_step, csptr, Sscore);
  kE<<<L_*DCH, 256, 0, stream>>>(S_ex, Sscore, bank_step, csptr, out, (float)k);
}

// Round 4
// 195.586 us; speedup vs baseline: 2.4691x; 1.0014x over previous
//
#include <hip/hip_runtime.h>
#include <cmath>
#include <climits>

// Fixed problem shape (from setup_inputs)
#define L_    8
#define B_    4
#define T_    2048
#define D_    1024
#define TTL_  1024
#define KSLOT 512          // max events per batch (k=410 total, so safe)
#define TC2   128          // t-chunk for main kernel
#define NCH2  (T_/TC2)     // 16
#define DCH   4            // D_/256 (used by small kernels)
#define ES    8            // event-split for excess kernel
#define SCH   8            // s-split for score kernel
#define TIEMAX 256

__device__ __forceinline__ int waveRed(int v){
  for(int o=32;o>0;o>>=1) v += __shfl_xor(v,o,64);
  return v;
}

// ---------------------------------------------------------------------------
// Kernel A: zero accumulators (replaces graph-hostile hipMemsetAsync),
// top-k event selection (exact jax.lax.top_k tie-breaking),
// per-batch sorted event lists, and global weight w[s].
// One block, 1024 threads.
// ---------------------------------------------------------------------------
__global__ __launch_bounds__(1024) void kA(
    const float* __restrict__ pressure, const int* __restrict__ hptr,
    int k, int* __restrict__ evT, int* __restrict__ meta, float* __restrict__ w,
    float4* __restrict__ zeroRegion /* S_all..Sscore, 32768 floats */)
{
  // zero the 128KB accumulator region (8192 float4)
  {
    float4 z = {0,0,0,0};
    #pragma unroll
    for(int j=0;j<8;++j) zeroRegion[threadIdx.x + j*1024] = z;
  }

  __shared__ unsigned ku[B_*T_];
  __shared__ short ef[B_*T_];
  __shared__ int csum[1024];
  __shared__ int scnt;
  __shared__ int s_n[B_];
  __shared__ int tieIdx[TIEMAX];
  __shared__ int tieCnt;
  const int tid = threadIdx.x;
  const int total = B_*T_;

  for(int i=tid;i<total;i+=1024){
    union{float f;unsigned u;} v; v.f = pressure[i];
    unsigned u = v.u;
    ku[i] = (u & 0x80000000u) ? ~u : (u | 0x80000000u);  // monotonic key
  }
  if(tid < B_) s_n[tid] = 0;
  if(tid == 0) tieCnt = 0;
  __syncthreads();

  // bitwise k-th largest: largest p with count(key >= p) >= k
  unsigned p = 0;
  for(int bit=31;bit>=0;--bit){
    unsigned test = p | (1u<<bit);
    if(tid==0) scnt = 0;
    __syncthreads();
    int c=0;
    for(int i=tid;i<total;i+=1024) c += (ku[i] >= test) ? 1 : 0;
    c = waveRed(c);
    if((tid&63)==0) atomicAdd(&scnt, c);
    __syncthreads();
    if(scnt >= k) p = test;
    __syncthreads();
  }
  if(tid==0) scnt=0;
  __syncthreads();
  {
    int c=0;
    for(int i=tid;i<total;i+=1024) c += (ku[i] > p) ? 1 : 0;
    c = waveRed(c);
    if((tid&63)==0) atomicAdd(&scnt, c);
  }
  // collect tie indices while counting strict-greater
  for(int i=tid;i<total;i+=1024){
    if(ku[i]==p){ int pos=atomicAdd(&tieCnt,1); if(pos<TIEMAX) tieIdx[pos]=i; }
  }
  __syncthreads();
  const int needed = k - scnt;   // ties to select, lowest flat index first

  // base event flags (strict greater)
  for(int j=0;j<8;++j){
    int i = tid*8+j;
    ef[i] = (ku[i] > p) ? (short)1 : (short)0;
  }
  __syncthreads();

  if(tieCnt <= TIEMAX){
    // serial selection of `needed` smallest tie indices (tieCnt tiny in practice)
    if(tid==0){
      int cnt = tieCnt;
      for(int sel=0; sel<needed; ++sel){
        int best=INT_MAX, bi=-1;
        for(int q=0;q<cnt;++q){ int vv=tieIdx[q]; if(vv>=0 && vv<best){best=vv;bi=q;} }
        if(bi>=0){ tieIdx[bi]=-1; ef[best]=1; }
      }
    }
  } else {
    // pathological fallback: per-element rank scan (correct, slow, never hit)
    for(int j=0;j<8;++j){
      int i = tid*8+j;
      if(ku[i]==p){
        int r=0;
        for(int q=0;q<i;++q) r += (ku[q]==p) ? 1 : 0;
        if(r < needed) ef[i]=1;
      }
    }
  }
  __syncthreads();

  // per-thread counts over final flags
  {
    int local=0;
    for(int j=0;j<8;++j) local += ef[tid*8+j];
    csum[tid]=local;
  }
  __syncthreads();

  // build per-batch sorted event lists (skip te == T-1: fe there is 0)
  for(int j=0;j<8;++j){
    int i = tid*8+j;
    if(ef[i]){
      int b = i / T_, t = i % T_;
      if(t != T_-1){
        int m = 0;
        int ch = i>>3;
        for(int q=(b*T_)>>3; q<ch; ++q) m += csum[q];
        for(int q=ch<<3; q<i; ++q) m += ef[q];
        evT[b*KSLOT + m] = t;
        atomicAdd(&s_n[b], 1);
      }
    }
  }
  __syncthreads();
  if(tid==0){
    int off=0;
    for(int b=0;b<B_;++b){ meta[b]=s_n[b]; meta[4+b]=off; off += s_n[b]; }
    meta[8] = off;  // total listed events
  }

  // w[s] = sum_{t'=max(0,s-H)}^{s-1} 1/min(H, T-1-t')
  const int H = hptr[0];
  for(int s=tid;s<T_;s+=1024){
    float acc = 0.f;
    int lo = s - H; if(lo < 0) lo = 0;
    for(int t2=lo; t2<s; ++t2){
      int c2 = T_-1-t2; if(c2 > H) c2 = H;
      acc += 1.0f / (float)c2;
    }
    w[s] = acc;
  }
}

// ---------------------------------------------------------------------------
// Kernel B: main streaming pass over states.
// Batch-8 register double-buffered loads; marks behind uniform batch guard
// so the steady-state loop has NO conditional memory ops (counted vmcnt).
// One block per (l,b,tchunk); 256 threads x float4 = full 1024-d row per t.
// ---------------------------------------------------------------------------
__global__ __launch_bounds__(256) void kB(
    const float* __restrict__ states, const float* __restrict__ w,
    const int* __restrict__ evT, const int* __restrict__ meta,
    const int* __restrict__ hptr,
    float* __restrict__ S_all, float* __restrict__ S_ev, float* __restrict__ ckpt)
{
  int bx = blockIdx.x;
  const int tch = bx % NCH2; bx /= NCH2;
  const int b = bx % B_;  const int l = bx / B_;
  const int tid = threadIdx.x;
  const int H = hptr[0];
  const int t0 = tch*TC2, t1 = t0+TC2;

  __shared__ float wloc[TC2];
  __shared__ int   sTe[KSLOT];
  __shared__ int   sEn[TC2+2];
  __shared__ int   sSl[TC2+2];
  __shared__ float sInv[TC2+2];

  const int n = meta[b], off = meta[4+b];
  for(int i=tid;i<TC2;i+=256) wloc[i] = w[t0+i];
  for(int i=tid;i<n;i+=256)   sTe[i]  = evT[b*KSLOT+i];
  __syncthreads();
  // ranks via block-wide counts (list is sorted): m0 = #(te<t0), m1 = #(te<t1)
  int a0 = (tid      < n && sTe[tid]      < t0) ? 1 : 0;
  int a1 = (tid+256  < n && sTe[tid+256]  < t0) ? 1 : 0;
  int b0 = (tid      < n && sTe[tid]      < t1) ? 1 : 0;
  int b1 = (tid+256  < n && sTe[tid+256]  < t1) ? 1 : 0;
  const int m0 = __syncthreads_count(a0) + __syncthreads_count(a1);
  const int m1 = __syncthreads_count(b0) + __syncthreads_count(b1);
  const int nev = m1 - m0;
  for(int j=tid;j<nev;j+=256){
    int te = sTe[m0+j];
    int c = T_-1-te; if(c>H) c=H;     // c >= 1 (te != T-1 excluded)
    sEn[j]  = te + c;
    sSl[j]  = off + m0 + j;
    sInv[j] = 1.0f/(float)c;
  }
  __syncthreads();

  int tmax = t1-1+H; if(tmax > T_-1) tmax = T_-1;
  const int len = tmax - t0 + 1;
  const int nfull = len >> 3;       // full batches of 8 (len%8==0 when H=64)
  const float4* sp = (const float4*)(states + ((size_t)(l*B_+b)*T_)*D_) + tid;

  float4 R = {0,0,0,0}, A = {0,0,0,0}, E = {0,0,0,0};
  int i0 = 0, i1 = 0;
  int nextS = (nev > 0) ? sTe[m0] : INT_MAX;
  int nextE = (nev > 0) ? sEn[0]  : INT_MAX;

  float4 v[8], u[8];
  if(nfull > 0){
    #pragma unroll
    for(int j=0;j<8;++j) v[j] = sp[(size_t)(t0+j)*256];
  }
  for(int nb=0; nb<nfull; ++nb){
    const int tb = t0 + nb*8;
    if(nb+1 < nfull){
      #pragma unroll
      for(int j=0;j<8;++j) u[j] = sp[(size_t)(tb+8+j)*256];
    }
    const bool hasMark = (nextS < tb+8) || (nextE < tb+8);
    if(!hasMark){
      // fast path: pure register math, no conditional memory ops
      #pragma unroll
      for(int j=0;j<8;++j){
        float4 x = v[j];
        float sx=x.x*x.x, sy=x.y*x.y, sz=x.z*x.z, sw=x.w*x.w;
        R.x+=sx; R.y+=sy; R.z+=sz; R.w+=sw;
        const int idx = tb + j - t0;
        const float wv = (idx < TC2) ? wloc[idx] : 0.0f;
        A.x=fmaf(wv,sx,A.x); A.y=fmaf(wv,sy,A.y);
        A.z=fmaf(wv,sz,A.z); A.w=fmaf(wv,sw,A.w);
      }
    } else {
      #pragma unroll
      for(int j=0;j<8;++j){
        float4 x = v[j];
        float sx=x.x*x.x, sy=x.y*x.y, sz=x.z*x.z, sw=x.w*x.w;
        R.x+=sx; R.y+=sy; R.z+=sz; R.w+=sw;
        const int idx = tb + j - t0;
        const float wv = (idx < TC2) ? wloc[idx] : 0.0f;
        A.x=fmaf(wv,sx,A.x); A.y=fmaf(wv,sy,A.y);
        A.z=fmaf(wv,sz,A.z); A.w=fmaf(wv,sw,A.w);
        const int t = tb + j;
        if(t == nextS){
          float4* cp = (float4*)(ckpt + ((size_t)l*KSLOT + sSl[i0])*D_) + tid;
          *cp = R;
          ++i0; nextS = (i0 < nev) ? sTe[m0+i0] : INT_MAX;
        }
        while(t == nextE){
          float4* cp = (float4*)(ckpt + ((size_t)l*KSLOT + sSl[i1])*D_) + tid;
          float4 st = *cp;
          const float inv = sInv[i1];
          float4 fe = {(R.x-st.x)*inv, (R.y-st.y)*inv, (R.z-st.z)*inv, (R.w-st.w)*inv};
          *cp = fe;
          E.x+=fe.x; E.y+=fe.y; E.z+=fe.z; E.w+=fe.w;
          ++i1; nextE = (i1 < nev) ? sEn[i1] : INT_MAX;
        }
      }
    }
    #pragma unroll
    for(int j=0;j<8;++j) v[j] = u[j];
  }
  // generic-H tail (not executed when H=64: len is a multiple of 8)
  for(int t=t0+nfull*8; t<=tmax; ++t){
    float4 x = sp[(size_t)t*256];
    float sx=x.x*x.x, sy=x.y*x.y, sz=x.z*x.z, sw=x.w*x.w;
    R.x+=sx; R.y+=sy; R.z+=sz; R.w+=sw;
    const int idx = t - t0;
    const float wv = (idx < TC2) ? wloc[idx] : 0.0f;
    A.x=fmaf(wv,sx,A.x); A.y=fmaf(wv,sy,A.y);
    A.z=fmaf(wv,sz,A.z); A.w=fmaf(wv,sw,A.w);
    if(t == nextS){
      float4* cp = (float4*)(ckpt + ((size_t)l*KSLOT + sSl[i0])*D_) + tid;
      *cp = R;
      ++i0; nextS = (i0 < nev) ? sTe[m0+i0] : INT_MAX;
    }
    while(t == nextE){
      float4* cp = (float4*)(ckpt + ((size_t)l*KSLOT + sSl[i1])*D_) + tid;
      float4 st = *cp;
      const float inv = sInv[i1];
      float4 fe = {(R.x-st.x)*inv, (R.y-st.y)*inv, (R.z-st.z)*inv, (R.w-st.w)*inv};
      *cp = fe;
      E.x+=fe.x; E.y+=fe.y; E.z+=fe.z; E.w+=fe.w;
      ++i1; nextE = (i1 < nev) ? sEn[i1] : INT_MAX;
    }
  }

  float* sa = S_all + l*D_ + tid*4;
  float* se = S_ev  + l*D_ + tid*4;
  atomicAdd(sa+0, A.x); atomicAdd(sa+1, A.y); atomicAdd(sa+2, A.z); atomicAdd(sa+3, A.w);
  atomicAdd(se+0, E.x); atomicAdd(se+1, E.y); atomicAdd(se+2, E.z); atomicAdd(se+3, E.w);
}

// ---------------------------------------------------------------------------
// Kernel D: baseline EMA + excess sum over events
// ---------------------------------------------------------------------------
__global__ __launch_bounds__(256) void kD(
    const float* __restrict__ ckpt, const int* __restrict__ meta,
    const float* __restrict__ S_all, const float* __restrict__ S_ev,
    const float* __restrict__ baseline, float* __restrict__ out,
    float* __restrict__ S_ex, int nonk)
{
  int bx = blockIdx.x;
  const int ech = bx % ES; bx /= ES;
  const int dch = bx % DCH; const int l = bx / DCH;
  const int tid = threadIdx.x;
  const int d = dch*256 + tid;
  const int i = l*D_ + d;
  const float obs = (S_all[i] - S_ev[i]) / (float)nonk;
  const float nb = 0.99f*baseline[i] + 0.01f*obs;
  if(ech == 0) out[L_*D_ + i] = nb;   // new_baseline output, written once
  const int nev = meta[8];
  const int chunk = (nev + ES - 1) / ES;
  const int e0 = ech*chunk;
  int e1 = e0 + chunk; if(e1 > nev) e1 = nev;
  if(e1 <= e0) return;
  float acc = 0.f;
  for(int e=e0;e<e1;++e){
    float fe = ckpt[((size_t)l*KSLOT + e)*D_ + d];
    acc += fmaxf(fe - nb, 0.f);
  }
  atomicAdd(&S_ex[l*D_+d], acc);
}

// ---------------------------------------------------------------------------
// Kernel S2: age-weighted bank sums (partial over s-chunks)
// ---------------------------------------------------------------------------
__global__ __launch_bounds__(256) void kS2(
    const float* __restrict__ bank_ev, const int* __restrict__ bank_step,
    const int* __restrict__ csptr, float* __restrict__ Sscore)
{
  int bx = blockIdx.x;
  const int sch = bx % SCH; bx /= SCH;
  const int dch = bx % DCH; const int l = bx / DCH;
  const int tid = threadIdx.x;
  const int d = dch*256 + tid;
  const int scount = TTL_/SCH;   // 128
  const int s0 = sch*scount;
  __shared__ float wl[256];
  const int cs = csptr[0];
  if(tid < scount){
    int bs = bank_step[l*TTL_ + s0 + tid];
    float wgt = 0.f;
    if(bs >= 0){
      int a = cs - bs; if(a < 0) a = 0;
      wgt = exp2f(-(float)a * (1.0f/256.0f));
    }
    wl[tid] = wgt;
  }
  __syncthreads();
  float acc0 = 0.f, acc1 = 0.f;
  const float* bp = bank_ev + ((size_t)l*TTL_ + s0)*D_ + d;
  for(int j=0;j<scount;j+=2){
    acc0 = fmaf(wl[j],   bp[(size_t)j*D_],     acc0);
    acc1 = fmaf(wl[j+1], bp[(size_t)(j+1)*D_], acc1);
  }
  atomicAdd(&Sscore[l*D_+d], acc0+acc1);
}

// ---------------------------------------------------------------------------
// Kernel E: finalize evidence -> out[0] and score -> out[2]
// ---------------------------------------------------------------------------
__global__ __launch_bounds__(256) void kE(
    const float* __restrict__ S_ex, const float* __restrict__ Sscore,
    const int* __restrict__ bank_step, const int* __restrict__ csptr,
    float* __restrict__ out, float kf)
{
  int bx = blockIdx.x;
  const int dch = bx % DCH; const int l = bx / DCH;
  const int tid = threadIdx.x;
  __shared__ float red[256];
  const int cs = csptr[0];
  float wacc = 0.f;
  for(int s=tid; s<TTL_; s+=256){
    int bs = bank_step[l*TTL_+s];
    if(bs >= 0){
      int a = cs - bs; if(a<0) a=0;
      wacc += exp2f(-(float)a * (1.0f/256.0f));
    }
  }
  red[tid] = wacc;
  __syncthreads();
  for(int st=128; st>0; st>>=1){ if(tid<st) red[tid] += red[tid+st]; __syncthreads(); }
  const float wsum = red[0];
  const int d = dch*256 + tid;
  const int i = l*D_ + d;
  out[i] = S_ex[i] / kf;
  float sc = 0.f;
  if(wsum > 0.f) sc = Sscore[i] / fmaxf(wsum, 1e-12f);
  out[2*L_*D_ + i] = sc;
}

// ---------------------------------------------------------------------------
extern "C" void kernel_launch(void* const* d_in, const int* in_sizes, int n_in,
                              void* d_out, int out_size, void* d_ws, size_t ws_size,
                              hipStream_t stream)
{
  const float* pressure  = (const float*)d_in[0];
  const float* states    = (const float*)d_in[1];
  const float* bank_ev   = (const float*)d_in[2];
  const float* baseline  = (const float*)d_in[3];
  const int*   bank_step = (const int*)d_in[4];
  const int*   csptr     = (const int*)d_in[5];
  const int*   hptr      = (const int*)d_in[6];
  float* out = (float*)d_out;

  const int total = B_*T_;
  const int k = (int)llround(0.05 * (double)total);   // 410

  // workspace layout
  char* ws = (char*)d_ws;
  float* w      = (float*)(ws + 0);        // T_ floats (8KB)
  int*   evT    = (int*)(ws + 8192);       // B_*KSLOT ints (8KB)
  int*   meta   = (int*)(ws + 16384);      // 16 ints
  float* S_all  = (float*)(ws + 32768);    // L*D (32KB)
  float* S_ev   = (float*)(ws + 65536);
  float* S_ex   = (float*)(ws + 98304);
  float* Sscore = (float*)(ws + 131072);
  float* ckpt   = (float*)(ws + 163840);   // L*KSLOT*D floats (16MB)

  const size_t need = 163840 + (size_t)L_*KSLOT*D_*sizeof(float);
  if(ws_size < need) return;

  // kA zeroes the 128KB accumulator region (S_all..Sscore) in-kernel:
  // a graph-captured hipMemsetAsync cost ~155us/replay (fillBufferAligned
  // node), vs ~2us of stores inside an already-running kernel.
  kA<<<1, 1024, 0, stream>>>(pressure, hptr, k, evT, meta, w, (float4*)S_all);
  kB<<<L_*B_*NCH2, 256, 0, stream>>>(states, w, evT, meta, hptr, S_all, S_ev, ckpt);
  kD<<<L_*DCH*ES, 256, 0, stream>>>(ckpt, meta, S_all, S_ev, baseline, out, S_ex, total - k);
  kS2<<<L_*DCH*SCH, 256, 0, stream>>>(bank_ev, bank_step, csptr, Sscore);
  kE<<<L_*DCH, 256, 0, stream>>>(S_ex, Sscore, bank_step, csptr, out, (float)k);
}

// Round 5
// 183.370 us; speedup vs baseline: 2.6336x; 1.0666x over previous
//
#include <hip/hip_runtime.h>
#include <cmath>
#include <climits>

// Fixed problem shape (from setup_inputs)
#define L_    8
#define B_    4
#define T_    2048
#define D_    1024
#define TTL_  1024
#define KSLOT 512          // max events per batch (k=410 total, so safe)
#define TC2   128          // t-chunk for main kernel
#define NCH2  (T_/TC2)     // 16
#define ES2   32           // event-split for excess kernel
#define SCH2  32           // s-split for score kernel
#define TIEMAX 256

__device__ __forceinline__ int waveRed(int v){
  for(int o=32;o>0;o>>=1) v += __shfl_xor(v,o,64);
  return v;
}

// ---------------------------------------------------------------------------
// Kernel A: zero accumulators, top-k selection (2-bit radix, exact
// jax.lax.top_k tie-breaking), per-batch sorted event lists, weight w[s].
// One block, 1024 threads.
// ---------------------------------------------------------------------------
__global__ __launch_bounds__(1024) void kA(
    const float* __restrict__ pressure, const int* __restrict__ hptr,
    int k, int* __restrict__ evT, int* __restrict__ meta, float* __restrict__ w,
    float4* __restrict__ zeroRegion /* S_all..Sscore, 32768 floats */)
{
  // zero the 128KB accumulator region (8192 float4)
  {
    float4 z = {0,0,0,0};
    #pragma unroll
    for(int j=0;j<8;++j) zeroRegion[threadIdx.x + j*1024] = z;
  }

  __shared__ unsigned ku[B_*T_];
  __shared__ short ef[B_*T_];
  __shared__ int csum[1024];
  __shared__ int cnt4[4][4];
  __shared__ int scnt;
  __shared__ int s_n[B_];
  __shared__ int tieIdx[TIEMAX];
  __shared__ int tieCnt;
  const int tid = threadIdx.x;
  const int total = B_*T_;

  for(int i=tid;i<total;i+=1024){
    union{float f;unsigned u;} v; v.f = pressure[i];
    unsigned u = v.u;
    ku[i] = (u & 0x80000000u) ? ~u : (u | 0x80000000u);  // monotonic key
  }
  if(tid < B_) s_n[tid] = 0;
  if(tid == 0) tieCnt = 0;
  if(tid < 8) ((int*)cnt4)[tid] = 0;   // zero cnt4[0], cnt4[1]
  __syncthreads();

  // 2-bit radix k-th-largest: 16 iterations, 1 barrier each.
  // invariant: count(keys >= p) >= k with bits below `bit` zero in p.
  unsigned p = 0;
  for(int it=0; it<16; ++it){
    const int bit = 30 - 2*it;
    int* A = cnt4[it&3];
    const unsigned q1 = p | (1u<<bit);
    const unsigned q2 = p | (2u<<bit);
    const unsigned q3 = p | (3u<<bit);
    int c1=0,c2=0,c3=0;
    for(int i=tid;i<total;i+=1024){
      unsigned x = ku[i];
      c1 += (x>=q1); c2 += (x>=q2); c3 += (x>=q3);
    }
    c1=waveRed(c1); c2=waveRed(c2); c3=waveRed(c3);
    if((tid&63)==0){ atomicAdd(&A[1],c1); atomicAdd(&A[2],c2); atomicAdd(&A[3],c3); }
    if(tid<4) cnt4[(it+2)&3][tid] = 0;   // zero buffer for iteration it+2
    __syncthreads();
    const int n1=A[1], n2=A[2], n3=A[3];
    if(n3>=k) p=q3; else if(n2>=k) p=q2; else if(n1>=k) p=q1;
    // no trailing barrier: next iter writes a different (pre-zeroed) buffer
  }
  __syncthreads();
  if(tid==0) scnt=0;
  __syncthreads();
  {
    int c=0;
    for(int i=tid;i<total;i+=1024) c += (ku[i] > p) ? 1 : 0;
    c = waveRed(c);
    if((tid&63)==0) atomicAdd(&scnt, c);
  }
  // collect tie indices while counting strict-greater
  for(int i=tid;i<total;i+=1024){
    if(ku[i]==p){ int pos=atomicAdd(&tieCnt,1); if(pos<TIEMAX) tieIdx[pos]=i; }
  }
  __syncthreads();
  const int needed = k - scnt;   // ties to select, lowest flat index first

  // base event flags (strict greater)
  for(int j=0;j<8;++j){
    int i = tid*8+j;
    ef[i] = (ku[i] > p) ? (short)1 : (short)0;
  }
  __syncthreads();

  if(tieCnt <= TIEMAX){
    if(tid==0){
      int cnt = tieCnt;
      for(int sel=0; sel<needed; ++sel){
        int best=INT_MAX, bi=-1;
        for(int q=0;q<cnt;++q){ int vv=tieIdx[q]; if(vv>=0 && vv<best){best=vv;bi=q;} }
        if(bi>=0){ tieIdx[bi]=-1; ef[best]=1; }
      }
    }
  } else {
    for(int j=0;j<8;++j){
      int i = tid*8+j;
      if(ku[i]==p){
        int r=0;
        for(int q=0;q<i;++q) r += (ku[q]==p) ? 1 : 0;
        if(r < needed) ef[i]=1;
      }
    }
  }
  __syncthreads();

  {
    int local=0;
    for(int j=0;j<8;++j) local += ef[tid*8+j];
    csum[tid]=local;
  }
  __syncthreads();

  // build per-batch sorted event lists (skip te == T-1: fe there is 0)
  for(int j=0;j<8;++j){
    int i = tid*8+j;
    if(ef[i]){
      int b = i / T_, t = i % T_;
      if(t != T_-1){
        int m = 0;
        int ch = i>>3;
        for(int q=(b*T_)>>3; q<ch; ++q) m += csum[q];
        for(int q=ch<<3; q<i; ++q) m += ef[q];
        evT[b*KSLOT + m] = t;
        atomicAdd(&s_n[b], 1);
      }
    }
  }
  __syncthreads();
  if(tid==0){
    int off=0;
    for(int b=0;b<B_;++b){ meta[b]=s_n[b]; meta[4+b]=off; off += s_n[b]; }
    meta[8] = off;  // total listed events
  }

  // w[s] = sum_{t'=max(0,s-H)}^{s-1} 1/min(H, T-1-t')
  const int H = hptr[0];
  for(int s=tid;s<T_;s+=1024){
    float acc = 0.f;
    int lo = s - H; if(lo < 0) lo = 0;
    for(int t2=lo; t2<s; ++t2){
      int c2 = T_-1-t2; if(c2 > H) c2 = H;
      acc += 1.0f / (float)c2;
    }
    w[s] = acc;
  }
}

// ---------------------------------------------------------------------------
// Kernel B: main streaming pass over states.
// Depth-2 register pipeline (3 rotating 8-row buffers), UNCONDITIONAL
// clamped prefetch -> compiler can emit counted vmcnt(16); marks behind a
// uniform per-batch guard. One block per (l,b,tchunk); 256 thr x float4.
// ---------------------------------------------------------------------------
#define LOADB(dst, tb_) { _Pragma("unroll") \
  for(int j=0;j<8;++j){ int tc=(tb_)+j; tc = (tc>tmax)?tmax:tc; \
    dst[j]=sp[(size_t)tc*256]; } }

#define COMPB(buf, tb_) { \
  const bool hasMark = (nextS < (tb_)+8) || (nextE < (tb_)+8); \
  if(!hasMark){ \
    _Pragma("unroll") for(int j=0;j<8;++j){ \
      float4 x=buf[j]; \
      float sx=x.x*x.x, sy=x.y*x.y, sz=x.z*x.z, sw=x.w*x.w; \
      R.x+=sx;R.y+=sy;R.z+=sz;R.w+=sw; \
      int idx=(tb_)+j-t0; idx = (idx>255)?255:idx; \
      const float wv=wloc[idx]; \
      A.x=fmaf(wv,sx,A.x);A.y=fmaf(wv,sy,A.y); \
      A.z=fmaf(wv,sz,A.z);A.w=fmaf(wv,sw,A.w); } \
  } else { \
    _Pragma("unroll") for(int j=0;j<8;++j){ \
      float4 x=buf[j]; \
      float sx=x.x*x.x, sy=x.y*x.y, sz=x.z*x.z, sw=x.w*x.w; \
      R.x+=sx;R.y+=sy;R.z+=sz;R.w+=sw; \
      int idx=(tb_)+j-t0; idx = (idx>255)?255:idx; \
      const float wv=wloc[idx]; \
      A.x=fmaf(wv,sx,A.x);A.y=fmaf(wv,sy,A.y); \
      A.z=fmaf(wv,sz,A.z);A.w=fmaf(wv,sw,A.w); \
      const int t = (tb_) + j; \
      if(t == nextS){ \
        float4* cp = (float4*)(ckpt + ((size_t)l*KSLOT + sSl[i0])*D_) + tid; \
        *cp = R; \
        ++i0; nextS = (i0 < nev) ? sTe[m0+i0] : INT_MAX; } \
      while(t == nextE){ \
        float4* cp = (float4*)(ckpt + ((size_t)l*KSLOT + sSl[i1])*D_) + tid; \
        float4 st = *cp; \
        const float inv = sInv[i1]; \
        float4 fe = {(R.x-st.x)*inv,(R.y-st.y)*inv,(R.z-st.z)*inv,(R.w-st.w)*inv}; \
        *cp = fe; \
        E.x+=fe.x;E.y+=fe.y;E.z+=fe.z;E.w+=fe.w; \
        ++i1; nextE = (i1 < nev) ? sEn[i1] : INT_MAX; } } \
  } }

__global__ __launch_bounds__(256) void kB(
    const float* __restrict__ states, const float* __restrict__ w,
    const int* __restrict__ evT, const int* __restrict__ meta,
    const int* __restrict__ hptr,
    float* __restrict__ S_all, float* __restrict__ S_ev, float* __restrict__ ckpt)
{
  int bx = blockIdx.x;
  const int tch = bx % NCH2; bx /= NCH2;
  const int b = bx % B_;  const int l = bx / B_;
  const int tid = threadIdx.x;
  const int H = hptr[0];
  const int t0 = tch*TC2, t1 = t0+TC2;

  __shared__ float wloc[256];          // zero-padded past TC2 -> branchless wv
  __shared__ int   sTe[KSLOT];
  __shared__ int   sEn[TC2+2];
  __shared__ int   sSl[TC2+2];
  __shared__ float sInv[TC2+2];

  const int n = meta[b], off = meta[4+b];
  wloc[tid] = (tid < TC2) ? w[t0+tid] : 0.0f;
  for(int i=tid;i<n;i+=256)   sTe[i]  = evT[b*KSLOT+i];
  __syncthreads();
  int a0 = (tid      < n && sTe[tid]      < t0) ? 1 : 0;
  int a1 = (tid+256  < n && sTe[tid+256]  < t0) ? 1 : 0;
  int b0 = (tid      < n && sTe[tid]      < t1) ? 1 : 0;
  int b1 = (tid+256  < n && sTe[tid+256]  < t1) ? 1 : 0;
  const int m0 = __syncthreads_count(a0) + __syncthreads_count(a1);
  const int m1 = __syncthreads_count(b0) + __syncthreads_count(b1);
  const int nev = m1 - m0;
  for(int j=tid;j<nev;j+=256){
    int te = sTe[m0+j];
    int c = T_-1-te; if(c>H) c=H;     // c >= 1 (te != T-1 excluded)
    sEn[j]  = te + c;
    sSl[j]  = off + m0 + j;
    sInv[j] = 1.0f/(float)c;
  }
  __syncthreads();

  int tmax = t1-1+H; if(tmax > T_-1) tmax = T_-1;
  const int len = tmax - t0 + 1;
  const int nfull = len >> 3;
  const float4* sp = (const float4*)(states + ((size_t)(l*B_+b)*T_)*D_) + tid;

  float4 R = {0,0,0,0}, A = {0,0,0,0}, E = {0,0,0,0};
  int i0 = 0, i1 = 0;
  int nextS = (nev > 0) ? sTe[m0] : INT_MAX;
  int nextE = (nev > 0) ? sEn[0]  : INT_MAX;

  float4 p0[8], p1[8], p2[8];
  LOADB(p0, t0);
  LOADB(p1, t0+8);
  int nb = 0;
  while(true){
    LOADB(p2, t0+(nb+2)*8); COMPB(p0, t0+nb*8); ++nb; if(nb>=nfull) break;
    LOADB(p0, t0+(nb+2)*8); COMPB(p1, t0+nb*8); ++nb; if(nb>=nfull) break;
    LOADB(p1, t0+(nb+2)*8); COMPB(p2, t0+nb*8); ++nb; if(nb>=nfull) break;
  }
  // generic-H tail (not executed when H=64: len is a multiple of 8)
  for(int t=t0+nfull*8; t<=tmax; ++t){
    float4 x = sp[(size_t)t*256];
    float sx=x.x*x.x, sy=x.y*x.y, sz=x.z*x.z, sw=x.w*x.w;
    R.x+=sx; R.y+=sy; R.z+=sz; R.w+=sw;
    int idx = t - t0; idx = (idx>255)?255:idx;
    const float wv = wloc[idx];
    A.x=fmaf(wv,sx,A.x); A.y=fmaf(wv,sy,A.y);
    A.z=fmaf(wv,sz,A.z); A.w=fmaf(wv,sw,A.w);
    if(t == nextS){
      float4* cp = (float4*)(ckpt + ((size_t)l*KSLOT + sSl[i0])*D_) + tid;
      *cp = R;
      ++i0; nextS = (i0 < nev) ? sTe[m0+i0] : INT_MAX;
    }
    while(t == nextE){
      float4* cp = (float4*)(ckpt + ((size_t)l*KSLOT + sSl[i1])*D_) + tid;
      float4 st = *cp;
      const float inv = sInv[i1];
      float4 fe = {(R.x-st.x)*inv, (R.y-st.y)*inv, (R.z-st.z)*inv, (R.w-st.w)*inv};
      *cp = fe;
      E.x+=fe.x; E.y+=fe.y; E.z+=fe.z; E.w+=fe.w;
      ++i1; nextE = (i1 < nev) ? sEn[i1] : INT_MAX;
    }
  }

  float* sa = S_all + l*D_ + tid*4;
  float* se = S_ev  + l*D_ + tid*4;
  atomicAdd(sa+0, A.x); atomicAdd(sa+1, A.y); atomicAdd(sa+2, A.z); atomicAdd(sa+3, A.w);
  atomicAdd(se+0, E.x); atomicAdd(se+1, E.y); atomicAdd(se+2, E.z); atomicAdd(se+3, E.w);
}

// ---------------------------------------------------------------------------
// Kernel D: baseline EMA + excess sum over events (float4/thread,
// independent pipelined loads; grid L_*ES2 = 256 blocks)
// ---------------------------------------------------------------------------
__global__ __launch_bounds__(256) void kD(
    const float4* __restrict__ ckpt4, const int* __restrict__ meta,
    const float4* __restrict__ S_all4, const float4* __restrict__ S_ev4,
    const float4* __restrict__ baseline4, float4* __restrict__ out4,
    float* __restrict__ S_ex, int nonk)
{
  const int l = blockIdx.x / ES2, ech = blockIdx.x % ES2;
  const int tid = threadIdx.x;
  const int i4 = l*256 + tid;
  const float inv_nonk = 1.0f/(float)nonk;
  const float4 sa = S_all4[i4], se = S_ev4[i4], bl = baseline4[i4];
  float4 nb;
  nb.x = 0.99f*bl.x + 0.01f*((sa.x-se.x)*inv_nonk);
  nb.y = 0.99f*bl.y + 0.01f*((sa.y-se.y)*inv_nonk);
  nb.z = 0.99f*bl.z + 0.01f*((sa.z-se.z)*inv_nonk);
  nb.w = 0.99f*bl.w + 0.01f*((sa.w-se.w)*inv_nonk);
  if(ech == 0) out4[(L_*D_/4) + i4] = nb;   // new_baseline output
  const int nev = meta[8];
  const int chunk = (nev + ES2 - 1) / ES2;
  const int e0 = ech*chunk;
  int e1 = e0 + chunk; if(e1 > nev) e1 = nev;
  if(e1 <= e0) return;
  float4 acc = {0,0,0,0};
  #pragma unroll 4
  for(int e=e0;e<e1;++e){
    float4 fe = ckpt4[((size_t)l*KSLOT + e)*256 + tid];
    acc.x += fmaxf(fe.x - nb.x, 0.f);
    acc.y += fmaxf(fe.y - nb.y, 0.f);
    acc.z += fmaxf(fe.z - nb.z, 0.f);
    acc.w += fmaxf(fe.w - nb.w, 0.f);
  }
  float* sx = S_ex + l*D_ + tid*4;
  atomicAdd(sx+0, acc.x); atomicAdd(sx+1, acc.y);
  atomicAdd(sx+2, acc.z); atomicAdd(sx+3, acc.w);
}

// ---------------------------------------------------------------------------
// Kernel S2: age-weighted bank sums (float4/thread, grid L_*SCH2 = 256)
// ---------------------------------------------------------------------------
__global__ __launch_bounds__(256) void kS2(
    const float4* __restrict__ bank_ev4, const int* __restrict__ bank_step,
    const int* __restrict__ csptr, float* __restrict__ Sscore)
{
  const int l = blockIdx.x / SCH2, sch = blockIdx.x % SCH2;
  const int tid = threadIdx.x;
  const int scount = TTL_/SCH2;   // 32
  const int s0 = sch*scount;
  __shared__ float wl[scount];
  const int cs = csptr[0];
  if(tid < scount){
    int bs = bank_step[l*TTL_ + s0 + tid];
    float wgt = 0.f;
    if(bs >= 0){
      int a = cs - bs; if(a < 0) a = 0;
      wgt = exp2f(-(float)a * (1.0f/256.0f));
    }
    wl[tid] = wgt;
  }
  __syncthreads();
  float4 acc = {0,0,0,0};
  const float4* bp = bank_ev4 + ((size_t)l*TTL_ + s0)*256 + tid;
  #pragma unroll 8
  for(int j=0;j<scount;++j){
    float4 v = bp[(size_t)j*256];
    const float wv = wl[j];
    acc.x = fmaf(wv, v.x, acc.x); acc.y = fmaf(wv, v.y, acc.y);
    acc.z = fmaf(wv, v.z, acc.z); acc.w = fmaf(wv, v.w, acc.w);
  }
  float* sp2 = Sscore + l*D_ + tid*4;
  atomicAdd(sp2+0, acc.x); atomicAdd(sp2+1, acc.y);
  atomicAdd(sp2+2, acc.z); atomicAdd(sp2+3, acc.w);
}

// ---------------------------------------------------------------------------
// Kernel E: finalize evidence -> out[0] and score -> out[2]  (grid = L_)
// ---------------------------------------------------------------------------
__global__ __launch_bounds__(256) void kE(
    const float4* __restrict__ S_ex4, const float4* __restrict__ Sscore4,
    const int* __restrict__ bank_step, const int* __restrict__ csptr,
    float4* __restrict__ out4, float kf)
{
  const int l = blockIdx.x;
  const int tid = threadIdx.x;
  __shared__ float red[256];
  const int cs = csptr[0];
  float wacc = 0.f;
  for(int s=tid; s<TTL_; s+=256){
    int bs = bank_step[l*TTL_+s];
    if(bs >= 0){
      int a = cs - bs; if(a<0) a=0;
      wacc += exp2f(-(float)a * (1.0f/256.0f));
    }
  }
  red[tid] = wacc;
  __syncthreads();
  for(int st=128; st>0; st>>=1){ if(tid<st) red[tid] += red[tid+st]; __syncthreads(); }
  const float wsum = red[0];
  const int i4 = l*256 + tid;
  const float invk = 1.0f/kf;
  float4 ex = S_ex4[i4];
  float4 o0 = {ex.x*invk, ex.y*invk, ex.z*invk, ex.w*invk};
  out4[i4] = o0;
  float4 ss = Sscore4[i4];
  float4 o2 = {0,0,0,0};
  if(wsum > 0.f){
    const float wm = fmaxf(wsum, 1e-12f);
    o2.x = ss.x/wm; o2.y = ss.y/wm; o2.z = ss.z/wm; o2.w = ss.w/wm;
  }
  out4[2*(L_*D_/4) + i4] = o2;
}

// ---------------------------------------------------------------------------
extern "C" void kernel_launch(void* const* d_in, const int* in_sizes, int n_in,
                              void* d_out, int out_size, void* d_ws, size_t ws_size,
                              hipStream_t stream)
{
  const float* pressure  = (const float*)d_in[0];
  const float* states    = (const float*)d_in[1];
  const float* bank_ev   = (const float*)d_in[2];
  const float* baseline  = (const float*)d_in[3];
  const int*   bank_step = (const int*)d_in[4];
  const int*   csptr     = (const int*)d_in[5];
  const int*   hptr      = (const int*)d_in[6];
  float* out = (float*)d_out;

  const int total = B_*T_;
  const int k = (int)llround(0.05 * (double)total);   // 410

  // workspace layout
  char* ws = (char*)d_ws;
  float* w      = (float*)(ws + 0);        // T_ floats (8KB)
  int*   evT    = (int*)(ws + 8192);       // B_*KSLOT ints (8KB)
  int*   meta   = (int*)(ws + 16384);      // 16 ints
  float* S_all  = (float*)(ws + 32768);    // L*D (32KB)
  float* S_ev   = (float*)(ws + 65536);
  float* S_ex   = (float*)(ws + 98304);
  float* Sscore = (float*)(ws + 131072);
  float* ckpt   = (float*)(ws + 163840);   // L*KSLOT*D floats (16MB)

  const size_t need = 163840 + (size_t)L_*KSLOT*D_*sizeof(float);
  if(ws_size < need) return;

  kA<<<1, 1024, 0, stream>>>(pressure, hptr, k, evT, meta, w, (float4*)S_all);
  kB<<<L_*B_*NCH2, 256, 0, stream>>>(states, w, evT, meta, hptr, S_all, S_ev, ckpt);
  kD<<<L_*ES2, 256, 0, stream>>>((const float4*)ckpt, meta, (const float4*)S_all,
                                 (const float4*)S_ev, (const float4*)baseline,
                                 (float4*)out, S_ex, total - k);
  kS2<<<L_*SCH2, 256, 0, stream>>>((const float4*)bank_ev, bank_step, csptr, Sscore);
  kE<<<L_, 256, 0, stream>>>((const float4*)S_ex, (const float4*)Sscore,
                             bank_step, csptr, (float4*)out, (float)k);
}